// Round 23
// baseline (394.751 us; speedup 1.0000x reference)
//
#include <hip/hip_runtime.h>

#define NN 50000
#define NE 800000
#define EP (NE + NN)      // edges + self loops (= 850000)
#define HID 128
#define FIN 64
#define NG 64
#define SLOPE 0.2f
#define NB 49             // scan blocks: 49*1024 >= NN
#define PREPN (NN * FIN / 4 + 2 * FIN * HID + 2 * HID * HID)
#define PREPB ((PREPN + 255) / 256)
#define HISTB 1024
#define GB ((NN + 63) / 64)   // gemm blocks (782)
#define SCATB 1024            // scatter blocks

typedef unsigned short ushort_t;
typedef unsigned int uint_t;
typedef __attribute__((ext_vector_type(8))) short bf16x8;
typedef __attribute__((ext_vector_type(4))) float f32x4;

__device__ __forceinline__ float wred_sum(float v) {
  for (int off = 32; off; off >>= 1) v += __shfl_xor(v, off);
  return v;
}
__device__ __forceinline__ ushort_t f2bf(float f) {   // RNE fp32 -> bf16
  uint_t b = __float_as_uint(f);
  b += 0x7fffu + ((b >> 16) & 1u);
  return (ushort_t)(b >> 16);
}
__device__ __forceinline__ float bf2f(ushort_t u) {
  return __uint_as_float((uint_t)u << 16);
}

// ---- fused prep (x->bf16 + 4x weight pack) AND edge histogram + mean -------
__global__ void k_prep(const float* __restrict__ x, ushort_t* __restrict__ x16,
                       const float* __restrict__ W1l, ushort_t* __restrict__ WP1l,
                       const float* __restrict__ W1r, ushort_t* __restrict__ WP1r,
                       const float* __restrict__ W2l, ushort_t* __restrict__ WP2l,
                       const float* __restrict__ W2r, ushort_t* __restrict__ WP2r,
                       const int* __restrict__ edst, const float* __restrict__ ew,
                       int* __restrict__ counts, float* __restrict__ meansum) {
  if (blockIdx.x >= PREPB) {
    int tid = (blockIdx.x - PREPB) * blockDim.x + threadIdx.x;
    int stride = HISTB * 256;
    float s = 0.f;
    for (int i = tid; i < NE; i += stride) {
      atomicAdd(&counts[edst[i]], 1);
      s += ew[i];
    }
    s = wred_sum(s);
    if ((threadIdx.x & 63) == 0) atomicAdd(meansum, s);
    return;
  }
  int i = blockIdx.x * blockDim.x + threadIdx.x;
  const int R0 = NN * FIN / 4;
  const int RS = FIN * HID;    // 8192
  const int RB = HID * HID;    // 16384
  if (i < R0) {
    float4 v = *(const float4*)(x + (size_t)i * 4);
    ushort4 u;
    u.x = f2bf(v.x); u.y = f2bf(v.y); u.z = f2bf(v.z); u.w = f2bf(v.w);
    *(ushort4*)(x16 + (size_t)i * 4) = u;
    return;
  }
  i -= R0;
  if (i < RS) {
    int k = i / HID, nn = i % HID;
    WP1l[((size_t)(k >> 5) * HID + nn) * 32 + (k & 31)] = f2bf(W1l[i]);
    return;
  }
  i -= RS;
  if (i < RS) {
    int k = i / HID, nn = i % HID;
    WP1r[((size_t)(k >> 5) * HID + nn) * 32 + (k & 31)] = f2bf(W1r[i]);
    return;
  }
  i -= RS;
  if (i < RB) {
    int k = i / HID, nn = i % HID;
    WP2l[((size_t)(k >> 5) * HID + nn) * 32 + (k & 31)] = f2bf(W2l[i]);
    return;
  }
  i -= RB;
  if (i < RB) {
    int k = i / HID, nn = i % HID;
    WP2r[((size_t)(k >> 5) * HID + nn) * 32 + (k & 31)] = f2bf(W2r[i]);
  }
}

// ---- hierarchical scan, stage 1: per-block local exclusive scan ------------
__global__ __launch_bounds__(1024) void k_scan1(const int* __restrict__ counts,
                                                int* __restrict__ starts,
                                                int* __restrict__ bsum) {
  __shared__ int wsum[16];
  __shared__ int woff[16];
  int t = threadIdx.x, lane = t & 63, w = t >> 6;
  int i = blockIdx.x * 1024 + t;
  int v = (i < NN) ? counts[i] + 1 : 0;   // +1 = self loop
  int sc = v;
  #pragma unroll
  for (int d = 1; d < 64; d <<= 1) {
    int u = __shfl_up(sc, d);
    if (lane >= d) sc += u;
  }
  if (lane == 63) wsum[w] = sc;
  __syncthreads();
  if (w == 0 && lane < 16) {
    int x = wsum[lane];
    #pragma unroll
    for (int d = 1; d < 16; d <<= 1) {
      int u = __shfl_up(x, d);
      if (lane >= d) x += u;
    }
    woff[lane] = x;
  }
  __syncthreads();
  int waveoff = (w == 0) ? 0 : woff[w - 1];
  if (i < NN) starts[i] = waveoff + sc - v;
  if (t == 1023) bsum[blockIdx.x] = woff[15];
}

// ---- scan stage 2+3 fused: each block redundantly scans bsum, then adds ----
__global__ __launch_bounds__(1024) void k_scan3(int* __restrict__ starts,
                                                const int* __restrict__ bsum,
                                                int* __restrict__ counts,
                                                const int* __restrict__ batch,
                                                int* __restrict__ gs) {
  __shared__ int boff;
  int t = threadIdx.x;
  if (t < 64) {
    int v = (t < NB) ? bsum[t] : 0;    // inclusive block totals from scan1
    int sc = v;
    #pragma unroll
    for (int d = 1; d < 64; d <<= 1) {
      int u = __shfl_up(sc, d);
      if (t >= d) sc += u;
    }
    if (t == (int)blockIdx.x) boff = sc - v;   // exclusive prefix, NB<64
  }
  __syncthreads();
  int i = blockIdx.x * 1024 + t;
  if (i < NN) {
    starts[i] += boff;
    counts[i] = 0;
    int b = batch[i];
    if (i == 0) {
      starts[NN] = EP;
      for (int g = 0; g <= b; ++g) gs[g] = 0;
    }
    int bn = (i + 1 < NN) ? batch[i + 1] : NG;
    for (int g = b + 1; g <= bn; ++g) gs[g] = i + 1;
  }
}

// ---- dual bf16 MFMA GEMM body (shared by standalone + fused launches) ------
template <int K>
__device__ __forceinline__ void gemm_body(int bid, const ushort_t* __restrict__ A16,
                                          const ushort_t* __restrict__ WPl,
                                          const float* __restrict__ bl,
                                          const ushort_t* __restrict__ WPr,
                                          const float* __restrict__ br,
                                          ushort_t* __restrict__ xlout,
                                          float* __restrict__ xrout, int n) {
  int t = threadIdx.x;
  int wave = t >> 6, lane = t & 63;
  int m = lane & 15, kb = lane >> 4;
  int row0 = bid * 64 + wave * 16;
  int ra = min(row0 + m, n - 1);
  f32x4 acc[16];
  #pragma unroll
  for (int i = 0; i < 16; ++i) acc[i] = (f32x4)(0.f);
  #pragma unroll
  for (int kt = 0; kt < K / 32; ++kt) {
    bf16x8 a = *(const bf16x8*)(A16 + (size_t)ra * K + kt * 32 + kb * 8);
    #pragma unroll
    for (int nf = 0; nf < 8; ++nf) {
      bf16x8 bfr = *(const bf16x8*)(WPl + ((size_t)kt * HID + nf * 16 + m) * 32 + kb * 8);
      acc[nf] = __builtin_amdgcn_mfma_f32_16x16x32_bf16(a, bfr, acc[nf], 0, 0, 0);
    }
    #pragma unroll
    for (int nf = 0; nf < 8; ++nf) {
      bf16x8 bfr = *(const bf16x8*)(WPr + ((size_t)kt * HID + nf * 16 + m) * 32 + kb * 8);
      acc[8 + nf] = __builtin_amdgcn_mfma_f32_16x16x32_bf16(a, bfr, acc[8 + nf], 0, 0, 0);
    }
  }
  #pragma unroll
  for (int nf = 0; nf < 8; ++nf) {
    int col = nf * 16 + m;
    float bbl = bl[col], bbr = br[col];
    #pragma unroll
    for (int j = 0; j < 4; ++j) {
      int r = row0 + kb * 4 + j;
      if (r < n) {
        xlout[(size_t)r * HID + col] = f2bf(acc[nf][j] + bbl);
        xrout[(size_t)r * HID + col] = acc[8 + nf][j] + bbr;
      }
    }
  }
}

// ---- standalone dual GEMM (layer 2) -----------------------------------------
template <int K>
__global__ __launch_bounds__(256) void k_gemmM(const ushort_t* __restrict__ A16,
                                               const ushort_t* __restrict__ WPl,
                                               const float* __restrict__ bl,
                                               const ushort_t* __restrict__ WPr,
                                               const float* __restrict__ br,
                                               ushort_t* __restrict__ xlout,
                                               float* __restrict__ xrout, int n) {
  gemm_body<K>(blockIdx.x, A16, WPl, bl, WPr, br, xlout, xrout, n);
}

// ---- fused: layer-1 GEMM + edge scatter (independent, one launch) ----------
__global__ __launch_bounds__(256) void k_scatgemm(const ushort_t* __restrict__ A16,
                                                  const ushort_t* __restrict__ WPl,
                                                  const float* __restrict__ bl,
                                                  const ushort_t* __restrict__ WPr,
                                                  const float* __restrict__ br,
                                                  ushort_t* __restrict__ xlout,
                                                  float* __restrict__ xrout,
                                                  const int* __restrict__ esrc,
                                                  const int* __restrict__ edst,
                                                  const float* __restrict__ ew,
                                                  const float* __restrict__ meansum,
                                                  const int* __restrict__ starts,
                                                  int* __restrict__ cursor,
                                                  int2* __restrict__ emeta) {
  if (blockIdx.x < GB) {
    gemm_body<FIN>(blockIdx.x, A16, WPl, bl, WPr, br, xlout, xrout, NN);
    return;
  }
  float mw = meansum[0] * (1.0f / NE);
  int tid = (blockIdx.x - GB) * blockDim.x + threadIdx.x;
  int stride = SCATB * 256;
  for (int i = tid; i < EP; i += stride) {
    int s, d; float wv;
    if (i < NE) { s = esrc[i]; d = edst[i]; wv = ew[i]; }
    else        { s = d = i - NE; wv = mw; }
    int pos = starts[d] + atomicAdd(&cursor[d], 1);
    emeta[pos] = make_int2(s, __float_as_int(wv));
  }
}

// ---- fully fused GATv2 edge phase (node per wave, half-wave float4) ---------
// (256,5): caps unified budget at 102 regs/lane — final bisection cell.
// Footprint known in (85,128]: if <=102 this gives 5 waves/SIMD, no spill.
// SPILL SENTINEL: WRITE_SIZE must stay ~12.5 MB; else revert to (256,4).
__global__ __launch_bounds__(256, 5) void k_fused(const ushort_t* __restrict__ xl16,
                                                  const float* __restrict__ xr,
                                                  const int2* __restrict__ emeta,
                                                  const int* __restrict__ starts,
                                                  const float* __restrict__ We,
                                                  const float* __restrict__ att,
                                                  const float* __restrict__ bias,
                                                  ushort_t* __restrict__ hout) {
  int node = blockIdx.x * (blockDim.x >> 6) + (threadIdx.x >> 6);
  int lane = threadIdx.x & 63;
  if (node >= NN) return;
  int hl = lane & 31;
  int half = lane >> 5;
  int s0 = starts[node], s1 = starts[node + 1];
  int f = hl * 4;
  float4 xro = *(const float4*)(xr + (size_t)node * HID + f);
  float4 we  = *(const float4*)(We + f);
  float4 at  = *(const float4*)(att + f);

  int emy = 8 * half + ((hl >> 2) & 7);   // edge whose folded logit lands here
  bool b4 = (hl & 16) != 0;
  bool b3 = (hl & 8) != 0;
  bool b2 = (hl & 4) != 0;

  float ssum = 0.f;
  float4 acc = make_float4(0.f, 0.f, 0.f, 0.f);

  for (int i0 = s0; i0 < s1; i0 += 16) {
    int base = i0 + 8 * half;
    uint2 g[8];
    float p[8];                          // holds edge weight, then logit
    #pragma unroll
    for (int k = 0; k < 8; ++k) {
      int idx = min(base + k, s1 - 1);
      int2 em = emeta[idx];              // uniform within half -> broadcast
      p[k] = __int_as_float(em.y);
      g[k] = *(const uint2*)(xl16 + (size_t)em.x * HID + f);
    }
    #pragma unroll
    for (int k = 0; k < 8; ++k) {
      float wk = p[k];
      float t0 = __uint_as_float(g[k].x << 16)          + xro.x + wk * we.x;
      float t1 = __uint_as_float(g[k].x & 0xffff0000u)  + xro.y + wk * we.y;
      float t2 = __uint_as_float(g[k].y << 16)          + xro.z + wk * we.z;
      float t3 = __uint_as_float(g[k].y & 0xffff0000u)  + xro.w + wk * we.w;
      t0 = t0 > 0.f ? t0 : SLOPE * t0;
      t1 = t1 > 0.f ? t1 : SLOPE * t1;
      t2 = t2 > 0.f ? t2 : SLOPE * t2;
      t3 = t3 > 0.f ? t3 : SLOPE * t3;
      p[k] = t0 * at.x + t1 * at.y + t2 * at.z + t3 * at.w;
    }
    // fold-reduce: 32-lane sums of 8 logits in 9 shfls
    float sdv, rcv;
    float q0, q1, q2, q3;
    sdv = b4 ? p[0] : p[4]; rcv = __shfl_xor(sdv, 16, 32); q0 = (b4 ? p[4] : p[0]) + rcv;
    sdv = b4 ? p[1] : p[5]; rcv = __shfl_xor(sdv, 16, 32); q1 = (b4 ? p[5] : p[1]) + rcv;
    sdv = b4 ? p[2] : p[6]; rcv = __shfl_xor(sdv, 16, 32); q2 = (b4 ? p[6] : p[2]) + rcv;
    sdv = b4 ? p[3] : p[7]; rcv = __shfl_xor(sdv, 16, 32); q3 = (b4 ? p[7] : p[3]) + rcv;
    float r0, r1;
    sdv = b3 ? q0 : q2; rcv = __shfl_xor(sdv, 8, 32); r0 = (b3 ? q2 : q0) + rcv;
    sdv = b3 ? q1 : q3; rcv = __shfl_xor(sdv, 8, 32); r1 = (b3 ? q3 : q1) + rcv;
    sdv = b2 ? r0 : r1; rcv = __shfl_xor(sdv, 4, 32);
    float lg = (b2 ? r1 : r0) + rcv;
    lg += __shfl_xor(lg, 1, 32);
    lg += __shfl_xor(lg, 2, 32);
    // lg = full logit of edge (i0 + emy), replicated on 4 lanes
    float w = (i0 + emy < s1) ? __expf(lg) : 0.f;
    ssum += w;
    #pragma unroll
    for (int k = 0; k < 8; ++k) {
      float wk = __shfl(w, k << 2, 32);
      acc.x += wk * __uint_as_float(g[k].x << 16);
      acc.y += wk * __uint_as_float(g[k].x & 0xffff0000u);
      acc.z += wk * __uint_as_float(g[k].y << 16);
      acc.w += wk * __uint_as_float(g[k].y & 0xffff0000u);
    }
  }
  // merge halves (features duplicated across halves, edges disjoint)
  acc.x += __shfl_xor(acc.x, 32);
  acc.y += __shfl_xor(acc.y, 32);
  acc.z += __shfl_xor(acc.z, 32);
  acc.w += __shfl_xor(acc.w, 32);
  float st = wred_sum(ssum) * 0.25f;   // each edge's w counted on 4 lanes
  float inv = 1.0f / st;
  if (half == 0) {
    float4 bb = *(const float4*)(bias + f);
    ushort4 u;
    u.x = f2bf(fmaxf(acc.x * inv + bb.x, 0.f));
    u.y = f2bf(fmaxf(acc.y * inv + bb.y, 0.f));
    u.z = f2bf(fmaxf(acc.z * inv + bb.z, 0.f));
    u.w = f2bf(fmaxf(acc.w * inv + bb.w, 0.f));
    *(ushort4*)(hout + (size_t)node * HID + f) = u;
  }
}

// ---- segmented mean pool (bf16 input) + final linear ------------------------
__global__ __launch_bounds__(256) void k_pool(const ushort_t* __restrict__ h,
                                              const int* __restrict__ gs,
                                              const float* __restrict__ Wlin,
                                              const float* __restrict__ blin,
                                              float* __restrict__ out) {
  __shared__ float red[256];
  int g = blockIdx.x;
  int t = threadIdx.x;
  int f = t & 127;
  int half = t >> 7;           // 0 or 1
  int n0 = gs[g], n1 = gs[g + 1];
  float s0 = 0.f, s1 = 0.f, s2 = 0.f, s3 = 0.f;
  int n = n0 + half;
  for (; n + 6 < n1; n += 8) {
    s0 += bf2f(h[(size_t)n * HID + f]);
    s1 += bf2f(h[(size_t)(n + 2) * HID + f]);
    s2 += bf2f(h[(size_t)(n + 4) * HID + f]);
    s3 += bf2f(h[(size_t)(n + 6) * HID + f]);
  }
  for (; n < n1; n += 2) s0 += bf2f(h[(size_t)n * HID + f]);
  red[t] = (s0 + s1) + (s2 + s3);
  __syncthreads();
  if (t < 128) {
    float pooled = red[t] + red[t + 128];
    float cnt = (float)max(n1 - n0, 1);
    red[t] = (pooled / cnt) * Wlin[f];
  }
  __syncthreads();
  if (t < 64) {
    float v = red[t] + red[t + 64];
    v = wred_sum(v);
    if (t == 0) out[g] = v + blin[0];
  }
}

extern "C" void kernel_launch(void* const* d_in, const int* in_sizes, int n_in,
                              void* d_out, int out_size, void* d_ws, size_t ws_size,
                              hipStream_t stream) {
  const float* x     = (const float*)d_in[0];
  const int*   ei    = (const int*)d_in[1];      // [2][NE]
  const float* ew    = (const float*)d_in[2];
  const int*   batch = (const int*)d_in[3];
  const float* W1l = (const float*)d_in[4];
  const float* b1l = (const float*)d_in[5];
  const float* W1r = (const float*)d_in[6];
  const float* b1r = (const float*)d_in[7];
  const float* We1 = (const float*)d_in[8];
  const float* at1 = (const float*)d_in[9];
  const float* bi1 = (const float*)d_in[10];
  const float* W2l = (const float*)d_in[11];
  const float* b2l = (const float*)d_in[12];
  const float* W2r = (const float*)d_in[13];
  const float* b2r = (const float*)d_in[14];
  const float* We2 = (const float*)d_in[15];
  const float* at2 = (const float*)d_in[16];
  const float* bi2 = (const float*)d_in[17];
  const float* Wlin = (const float*)d_in[18];
  const float* blin = (const float*)d_in[19];

  float* ws = (float*)d_ws;
  size_t o = 0;
  float*    xr    = ws + o; o += (size_t)NN * HID;
  ushort_t* xl16  = (ushort_t*)(ws + o); o += (size_t)NN * HID / 2;
  ushort_t* hb16  = (ushort_t*)(ws + o); o += (size_t)NN * HID / 2;
  ushort_t* x16   = (ushort_t*)(ws + o); o += (size_t)NN * FIN / 2;
  ushort_t* WP1l  = (ushort_t*)(ws + o); o += (size_t)FIN * HID / 2;
  ushort_t* WP1r  = (ushort_t*)(ws + o); o += (size_t)FIN * HID / 2;
  ushort_t* WP2l  = (ushort_t*)(ws + o); o += (size_t)HID * HID / 2;
  ushort_t* WP2r  = (ushort_t*)(ws + o); o += (size_t)HID * HID / 2;
  int2*     emeta = (int2*)(ws + o); o += (size_t)2 * EP;
  int*      starts = (int*)(ws + o); o += NN + 1;
  int*      gs     = (int*)(ws + o); o += NG + 1;
  int*      bsum   = (int*)(ws + o); o += NB;
  size_t zoff = o;
  int*      counts  = (int*)(ws + o); o += NN;
  float*    meansum = ws + o; o += 1;
  size_t zero_bytes = (o - zoff) * sizeof(float);

  hipMemsetAsync(counts, 0, zero_bytes, stream);

  // prep (convert + pack) and edge histogram/mean in ONE launch
  k_prep<<<PREPB + HISTB, 256, 0, stream>>>(x, x16, W1l, WP1l, W1r, WP1r,
                                            W2l, WP2l, W2r, WP2r,
                                            ei + NE, ew, counts, meansum);

  // build dst-sorted CSR starts + graph bounds
  k_scan1<<<NB, 1024, 0, stream>>>(counts, starts, bsum);
  k_scan3<<<NB, 1024, 0, stream>>>(starts, bsum, counts, batch, gs);

  int nbn = (NN + 3) / 4;                         // node-per-wave blocks

  // layer-1 GEMM and edge scatter overlapped in ONE launch (independent)
  k_scatgemm<<<GB + SCATB, 256, 0, stream>>>(x16, WP1l, b1l, WP1r, b1r,
                                             xl16, xr, ei, ei + NE, ew,
                                             meansum, starts, counts, emeta);
  k_fused<<<nbn, 256, 0, stream>>>(xl16, xr, emeta, starts, We1, at1, bi1, hb16);
  // layer 2
  k_gemmM<HID><<<GB, 256, 0, stream>>>(hb16, WP2l, b2l, WP2r, b2r, xl16, xr, NN);
  k_fused<<<nbn, 256, 0, stream>>>(xl16, xr, emeta, starts, We2, at2, bi2, hb16);
  // pool + head (no atomics: batch is sorted -> contiguous graph ranges)
  k_pool<<<NG, 256, 0, stream>>>(hb16, gs, Wlin, blin, (float*)d_out);
}

// Round 24
// 366.691 us; speedup vs baseline: 1.0765x; 1.0765x over previous
//
#include <hip/hip_runtime.h>

#define NN 50000
#define NE 800000
#define EP (NE + NN)      // edges + self loops (= 850000)
#define HID 128
#define FIN 64
#define NG 64
#define SLOPE 0.2f
#define NB 49             // scan blocks: 49*1024 >= NN
#define PREPN (NN * FIN / 4 + 2 * FIN * HID + 2 * HID * HID)
#define PREPB ((PREPN + 255) / 256)
#define HISTB 1024
#define GB ((NN + 63) / 64)   // gemm blocks (782)
#define SCATB 1024            // scatter blocks

typedef unsigned short ushort_t;
typedef unsigned int uint_t;
typedef __attribute__((ext_vector_type(8))) short bf16x8;
typedef __attribute__((ext_vector_type(4))) float f32x4;

__device__ __forceinline__ float wred_sum(float v) {
  for (int off = 32; off; off >>= 1) v += __shfl_xor(v, off);
  return v;
}
__device__ __forceinline__ ushort_t f2bf(float f) {   // RNE fp32 -> bf16
  uint_t b = __float_as_uint(f);
  b += 0x7fffu + ((b >> 16) & 1u);
  return (ushort_t)(b >> 16);
}
__device__ __forceinline__ float bf2f(ushort_t u) {
  return __uint_as_float((uint_t)u << 16);
}

// ---- fused prep (x->bf16 + 4x weight pack) AND edge histogram + mean -------
__global__ void k_prep(const float* __restrict__ x, ushort_t* __restrict__ x16,
                       const float* __restrict__ W1l, ushort_t* __restrict__ WP1l,
                       const float* __restrict__ W1r, ushort_t* __restrict__ WP1r,
                       const float* __restrict__ W2l, ushort_t* __restrict__ WP2l,
                       const float* __restrict__ W2r, ushort_t* __restrict__ WP2r,
                       const int* __restrict__ edst, const float* __restrict__ ew,
                       int* __restrict__ counts, float* __restrict__ meansum) {
  if (blockIdx.x >= PREPB) {
    int tid = (blockIdx.x - PREPB) * blockDim.x + threadIdx.x;
    int stride = HISTB * 256;
    float s = 0.f;
    for (int i = tid; i < NE; i += stride) {
      atomicAdd(&counts[edst[i]], 1);
      s += ew[i];
    }
    s = wred_sum(s);
    if ((threadIdx.x & 63) == 0) atomicAdd(meansum, s);
    return;
  }
  int i = blockIdx.x * blockDim.x + threadIdx.x;
  const int R0 = NN * FIN / 4;
  const int RS = FIN * HID;    // 8192
  const int RB = HID * HID;    // 16384
  if (i < R0) {
    float4 v = *(const float4*)(x + (size_t)i * 4);
    ushort4 u;
    u.x = f2bf(v.x); u.y = f2bf(v.y); u.z = f2bf(v.z); u.w = f2bf(v.w);
    *(ushort4*)(x16 + (size_t)i * 4) = u;
    return;
  }
  i -= R0;
  if (i < RS) {
    int k = i / HID, nn = i % HID;
    WP1l[((size_t)(k >> 5) * HID + nn) * 32 + (k & 31)] = f2bf(W1l[i]);
    return;
  }
  i -= RS;
  if (i < RS) {
    int k = i / HID, nn = i % HID;
    WP1r[((size_t)(k >> 5) * HID + nn) * 32 + (k & 31)] = f2bf(W1r[i]);
    return;
  }
  i -= RS;
  if (i < RB) {
    int k = i / HID, nn = i % HID;
    WP2l[((size_t)(k >> 5) * HID + nn) * 32 + (k & 31)] = f2bf(W2l[i]);
    return;
  }
  i -= RB;
  if (i < RB) {
    int k = i / HID, nn = i % HID;
    WP2r[((size_t)(k >> 5) * HID + nn) * 32 + (k & 31)] = f2bf(W2r[i]);
  }
}

// ---- hierarchical scan, stage 1: per-block local exclusive scan ------------
__global__ __launch_bounds__(1024) void k_scan1(const int* __restrict__ counts,
                                                int* __restrict__ starts,
                                                int* __restrict__ bsum) {
  __shared__ int wsum[16];
  __shared__ int woff[16];
  int t = threadIdx.x, lane = t & 63, w = t >> 6;
  int i = blockIdx.x * 1024 + t;
  int v = (i < NN) ? counts[i] + 1 : 0;   // +1 = self loop
  int sc = v;
  #pragma unroll
  for (int d = 1; d < 64; d <<= 1) {
    int u = __shfl_up(sc, d);
    if (lane >= d) sc += u;
  }
  if (lane == 63) wsum[w] = sc;
  __syncthreads();
  if (w == 0 && lane < 16) {
    int x = wsum[lane];
    #pragma unroll
    for (int d = 1; d < 16; d <<= 1) {
      int u = __shfl_up(x, d);
      if (lane >= d) x += u;
    }
    woff[lane] = x;
  }
  __syncthreads();
  int waveoff = (w == 0) ? 0 : woff[w - 1];
  if (i < NN) starts[i] = waveoff + sc - v;
  if (t == 1023) bsum[blockIdx.x] = woff[15];
}

// ---- scan stage 2+3 fused: each block redundantly scans bsum, then adds ----
__global__ __launch_bounds__(1024) void k_scan3(int* __restrict__ starts,
                                                const int* __restrict__ bsum,
                                                int* __restrict__ counts,
                                                const int* __restrict__ batch,
                                                int* __restrict__ gs) {
  __shared__ int boff;
  int t = threadIdx.x;
  if (t < 64) {
    int v = (t < NB) ? bsum[t] : 0;    // inclusive block totals from scan1
    int sc = v;
    #pragma unroll
    for (int d = 1; d < 64; d <<= 1) {
      int u = __shfl_up(sc, d);
      if (t >= d) sc += u;
    }
    if (t == (int)blockIdx.x) boff = sc - v;   // exclusive prefix, NB<64
  }
  __syncthreads();
  int i = blockIdx.x * 1024 + t;
  if (i < NN) {
    starts[i] += boff;
    counts[i] = 0;
    int b = batch[i];
    if (i == 0) {
      starts[NN] = EP;
      for (int g = 0; g <= b; ++g) gs[g] = 0;
    }
    int bn = (i + 1 < NN) ? batch[i + 1] : NG;
    for (int g = b + 1; g <= bn; ++g) gs[g] = i + 1;
  }
}

// ---- dual bf16 MFMA GEMM body (shared by standalone + fused launches) ------
template <int K>
__device__ __forceinline__ void gemm_body(int bid, const ushort_t* __restrict__ A16,
                                          const ushort_t* __restrict__ WPl,
                                          const float* __restrict__ bl,
                                          const ushort_t* __restrict__ WPr,
                                          const float* __restrict__ br,
                                          ushort_t* __restrict__ xlout,
                                          float* __restrict__ xrout, int n) {
  int t = threadIdx.x;
  int wave = t >> 6, lane = t & 63;
  int m = lane & 15, kb = lane >> 4;
  int row0 = bid * 64 + wave * 16;
  int ra = min(row0 + m, n - 1);
  f32x4 acc[16];
  #pragma unroll
  for (int i = 0; i < 16; ++i) acc[i] = (f32x4)(0.f);
  #pragma unroll
  for (int kt = 0; kt < K / 32; ++kt) {
    bf16x8 a = *(const bf16x8*)(A16 + (size_t)ra * K + kt * 32 + kb * 8);
    #pragma unroll
    for (int nf = 0; nf < 8; ++nf) {
      bf16x8 bfr = *(const bf16x8*)(WPl + ((size_t)kt * HID + nf * 16 + m) * 32 + kb * 8);
      acc[nf] = __builtin_amdgcn_mfma_f32_16x16x32_bf16(a, bfr, acc[nf], 0, 0, 0);
    }
    #pragma unroll
    for (int nf = 0; nf < 8; ++nf) {
      bf16x8 bfr = *(const bf16x8*)(WPr + ((size_t)kt * HID + nf * 16 + m) * 32 + kb * 8);
      acc[8 + nf] = __builtin_amdgcn_mfma_f32_16x16x32_bf16(a, bfr, acc[8 + nf], 0, 0, 0);
    }
  }
  #pragma unroll
  for (int nf = 0; nf < 8; ++nf) {
    int col = nf * 16 + m;
    float bbl = bl[col], bbr = br[col];
    #pragma unroll
    for (int j = 0; j < 4; ++j) {
      int r = row0 + kb * 4 + j;
      if (r < n) {
        xlout[(size_t)r * HID + col] = f2bf(acc[nf][j] + bbl);
        xrout[(size_t)r * HID + col] = acc[8 + nf][j] + bbr;
      }
    }
  }
}

// ---- standalone dual GEMM (layer 2) -----------------------------------------
template <int K>
__global__ __launch_bounds__(256) void k_gemmM(const ushort_t* __restrict__ A16,
                                               const ushort_t* __restrict__ WPl,
                                               const float* __restrict__ bl,
                                               const ushort_t* __restrict__ WPr,
                                               const float* __restrict__ br,
                                               ushort_t* __restrict__ xlout,
                                               float* __restrict__ xrout, int n) {
  gemm_body<K>(blockIdx.x, A16, WPl, bl, WPr, br, xlout, xrout, n);
}

// ---- fused: layer-1 GEMM + edge scatter (independent, one launch) ----------
__global__ __launch_bounds__(256) void k_scatgemm(const ushort_t* __restrict__ A16,
                                                  const ushort_t* __restrict__ WPl,
                                                  const float* __restrict__ bl,
                                                  const ushort_t* __restrict__ WPr,
                                                  const float* __restrict__ br,
                                                  ushort_t* __restrict__ xlout,
                                                  float* __restrict__ xrout,
                                                  const int* __restrict__ esrc,
                                                  const int* __restrict__ edst,
                                                  const float* __restrict__ ew,
                                                  const float* __restrict__ meansum,
                                                  const int* __restrict__ starts,
                                                  int* __restrict__ cursor,
                                                  int2* __restrict__ emeta) {
  if (blockIdx.x < GB) {
    gemm_body<FIN>(blockIdx.x, A16, WPl, bl, WPr, br, xlout, xrout, NN);
    return;
  }
  float mw = meansum[0] * (1.0f / NE);
  int tid = (blockIdx.x - GB) * blockDim.x + threadIdx.x;
  int stride = SCATB * 256;
  for (int i = tid; i < EP; i += stride) {
    int s, d; float wv;
    if (i < NE) { s = esrc[i]; d = edst[i]; wv = ew[i]; }
    else        { s = d = i - NE; wv = mw; }
    int pos = starts[d] + atomicAdd(&cursor[d], 1);
    emeta[pos] = make_int2(s, __float_as_int(wv));
  }
}

// ---- fully fused GATv2 edge phase (node per wave, half-wave float4) ---------
// Known-good (82.5 us, VGPR 60, no spill). Register bisection (r19/r20/r23):
// unified footprint in (102,128]; (256,4) is the ONLY non-spilling bracket.
__global__ __launch_bounds__(256, 4) void k_fused(const ushort_t* __restrict__ xl16,
                                                  const float* __restrict__ xr,
                                                  const int2* __restrict__ emeta,
                                                  const int* __restrict__ starts,
                                                  const float* __restrict__ We,
                                                  const float* __restrict__ att,
                                                  const float* __restrict__ bias,
                                                  ushort_t* __restrict__ hout) {
  int node = blockIdx.x * (blockDim.x >> 6) + (threadIdx.x >> 6);
  int lane = threadIdx.x & 63;
  if (node >= NN) return;
  int hl = lane & 31;
  int half = lane >> 5;
  int s0 = starts[node], s1 = starts[node + 1];
  int f = hl * 4;
  float4 xro = *(const float4*)(xr + (size_t)node * HID + f);
  float4 we  = *(const float4*)(We + f);
  float4 at  = *(const float4*)(att + f);

  int emy = 8 * half + ((hl >> 2) & 7);   // edge whose folded logit lands here
  bool b4 = (hl & 16) != 0;
  bool b3 = (hl & 8) != 0;
  bool b2 = (hl & 4) != 0;

  float ssum = 0.f;
  float4 acc = make_float4(0.f, 0.f, 0.f, 0.f);

  for (int i0 = s0; i0 < s1; i0 += 16) {
    int base = i0 + 8 * half;
    uint2 g[8];
    float p[8];                          // holds edge weight, then logit
    #pragma unroll
    for (int k = 0; k < 8; ++k) {
      int idx = min(base + k, s1 - 1);
      int2 em = emeta[idx];              // uniform within half -> broadcast
      p[k] = __int_as_float(em.y);
      g[k] = *(const uint2*)(xl16 + (size_t)em.x * HID + f);
    }
    #pragma unroll
    for (int k = 0; k < 8; ++k) {
      float wk = p[k];
      float t0 = __uint_as_float(g[k].x << 16)          + xro.x + wk * we.x;
      float t1 = __uint_as_float(g[k].x & 0xffff0000u)  + xro.y + wk * we.y;
      float t2 = __uint_as_float(g[k].y << 16)          + xro.z + wk * we.z;
      float t3 = __uint_as_float(g[k].y & 0xffff0000u)  + xro.w + wk * we.w;
      t0 = t0 > 0.f ? t0 : SLOPE * t0;
      t1 = t1 > 0.f ? t1 : SLOPE * t1;
      t2 = t2 > 0.f ? t2 : SLOPE * t2;
      t3 = t3 > 0.f ? t3 : SLOPE * t3;
      p[k] = t0 * at.x + t1 * at.y + t2 * at.z + t3 * at.w;
    }
    // fold-reduce: 32-lane sums of 8 logits in 9 shfls
    float sdv, rcv;
    float q0, q1, q2, q3;
    sdv = b4 ? p[0] : p[4]; rcv = __shfl_xor(sdv, 16, 32); q0 = (b4 ? p[4] : p[0]) + rcv;
    sdv = b4 ? p[1] : p[5]; rcv = __shfl_xor(sdv, 16, 32); q1 = (b4 ? p[5] : p[1]) + rcv;
    sdv = b4 ? p[2] : p[6]; rcv = __shfl_xor(sdv, 16, 32); q2 = (b4 ? p[6] : p[2]) + rcv;
    sdv = b4 ? p[3] : p[7]; rcv = __shfl_xor(sdv, 16, 32); q3 = (b4 ? p[7] : p[3]) + rcv;
    float r0, r1;
    sdv = b3 ? q0 : q2; rcv = __shfl_xor(sdv, 8, 32); r0 = (b3 ? q2 : q0) + rcv;
    sdv = b3 ? q1 : q3; rcv = __shfl_xor(sdv, 8, 32); r1 = (b3 ? q3 : q1) + rcv;
    sdv = b2 ? r0 : r1; rcv = __shfl_xor(sdv, 4, 32);
    float lg = (b2 ? r1 : r0) + rcv;
    lg += __shfl_xor(lg, 1, 32);
    lg += __shfl_xor(lg, 2, 32);
    // lg = full logit of edge (i0 + emy), replicated on 4 lanes
    float w = (i0 + emy < s1) ? __expf(lg) : 0.f;
    ssum += w;
    #pragma unroll
    for (int k = 0; k < 8; ++k) {
      float wk = __shfl(w, k << 2, 32);
      acc.x += wk * __uint_as_float(g[k].x << 16);
      acc.y += wk * __uint_as_float(g[k].x & 0xffff0000u);
      acc.z += wk * __uint_as_float(g[k].y << 16);
      acc.w += wk * __uint_as_float(g[k].y & 0xffff0000u);
    }
  }
  // merge halves (features duplicated across halves, edges disjoint)
  acc.x += __shfl_xor(acc.x, 32);
  acc.y += __shfl_xor(acc.y, 32);
  acc.z += __shfl_xor(acc.z, 32);
  acc.w += __shfl_xor(acc.w, 32);
  float st = wred_sum(ssum) * 0.25f;   // each edge's w counted on 4 lanes
  float inv = 1.0f / st;
  if (half == 0) {
    float4 bb = *(const float4*)(bias + f);
    ushort4 u;
    u.x = f2bf(fmaxf(acc.x * inv + bb.x, 0.f));
    u.y = f2bf(fmaxf(acc.y * inv + bb.y, 0.f));
    u.z = f2bf(fmaxf(acc.z * inv + bb.z, 0.f));
    u.w = f2bf(fmaxf(acc.w * inv + bb.w, 0.f));
    *(ushort4*)(hout + (size_t)node * HID + f) = u;
  }
}

// ---- segmented mean pool (bf16 input) + final linear ------------------------
__global__ __launch_bounds__(256) void k_pool(const ushort_t* __restrict__ h,
                                              const int* __restrict__ gs,
                                              const float* __restrict__ Wlin,
                                              const float* __restrict__ blin,
                                              float* __restrict__ out) {
  __shared__ float red[256];
  int g = blockIdx.x;
  int t = threadIdx.x;
  int f = t & 127;
  int half = t >> 7;           // 0 or 1
  int n0 = gs[g], n1 = gs[g + 1];
  float s0 = 0.f, s1 = 0.f, s2 = 0.f, s3 = 0.f;
  int n = n0 + half;
  for (; n + 6 < n1; n += 8) {
    s0 += bf2f(h[(size_t)n * HID + f]);
    s1 += bf2f(h[(size_t)(n + 2) * HID + f]);
    s2 += bf2f(h[(size_t)(n + 4) * HID + f]);
    s3 += bf2f(h[(size_t)(n + 6) * HID + f]);
  }
  for (; n < n1; n += 2) s0 += bf2f(h[(size_t)n * HID + f]);
  red[t] = (s0 + s1) + (s2 + s3);
  __syncthreads();
  if (t < 128) {
    float pooled = red[t] + red[t + 128];
    float cnt = (float)max(n1 - n0, 1);
    red[t] = (pooled / cnt) * Wlin[f];
  }
  __syncthreads();
  if (t < 64) {
    float v = red[t] + red[t + 64];
    v = wred_sum(v);
    if (t == 0) out[g] = v + blin[0];
  }
}

extern "C" void kernel_launch(void* const* d_in, const int* in_sizes, int n_in,
                              void* d_out, int out_size, void* d_ws, size_t ws_size,
                              hipStream_t stream) {
  const float* x     = (const float*)d_in[0];
  const int*   ei    = (const int*)d_in[1];      // [2][NE]
  const float* ew    = (const float*)d_in[2];
  const int*   batch = (const int*)d_in[3];
  const float* W1l = (const float*)d_in[4];
  const float* b1l = (const float*)d_in[5];
  const float* W1r = (const float*)d_in[6];
  const float* b1r = (const float*)d_in[7];
  const float* We1 = (const float*)d_in[8];
  const float* at1 = (const float*)d_in[9];
  const float* bi1 = (const float*)d_in[10];
  const float* W2l = (const float*)d_in[11];
  const float* b2l = (const float*)d_in[12];
  const float* W2r = (const float*)d_in[13];
  const float* b2r = (const float*)d_in[14];
  const float* We2 = (const float*)d_in[15];
  const float* at2 = (const float*)d_in[16];
  const float* bi2 = (const float*)d_in[17];
  const float* Wlin = (const float*)d_in[18];
  const float* blin = (const float*)d_in[19];

  float* ws = (float*)d_ws;
  size_t o = 0;
  float*    xr    = ws + o; o += (size_t)NN * HID;
  ushort_t* xl16  = (ushort_t*)(ws + o); o += (size_t)NN * HID / 2;
  ushort_t* hb16  = (ushort_t*)(ws + o); o += (size_t)NN * HID / 2;
  ushort_t* x16   = (ushort_t*)(ws + o); o += (size_t)NN * FIN / 2;
  ushort_t* WP1l  = (ushort_t*)(ws + o); o += (size_t)FIN * HID / 2;
  ushort_t* WP1r  = (ushort_t*)(ws + o); o += (size_t)FIN * HID / 2;
  ushort_t* WP2l  = (ushort_t*)(ws + o); o += (size_t)HID * HID / 2;
  ushort_t* WP2r  = (ushort_t*)(ws + o); o += (size_t)HID * HID / 2;
  int2*     emeta = (int2*)(ws + o); o += (size_t)2 * EP;
  int*      starts = (int*)(ws + o); o += NN + 1;
  int*      gs     = (int*)(ws + o); o += NG + 1;
  int*      bsum   = (int*)(ws + o); o += NB;
  size_t zoff = o;
  int*      counts  = (int*)(ws + o); o += NN;
  float*    meansum = ws + o; o += 1;
  size_t zero_bytes = (o - zoff) * sizeof(float);

  hipMemsetAsync(counts, 0, zero_bytes, stream);

  // prep (convert + pack) and edge histogram/mean in ONE launch
  k_prep<<<PREPB + HISTB, 256, 0, stream>>>(x, x16, W1l, WP1l, W1r, WP1r,
                                            W2l, WP2l, W2r, WP2r,
                                            ei + NE, ew, counts, meansum);

  // build dst-sorted CSR starts + graph bounds
  k_scan1<<<NB, 1024, 0, stream>>>(counts, starts, bsum);
  k_scan3<<<NB, 1024, 0, stream>>>(starts, bsum, counts, batch, gs);

  int nbn = (NN + 3) / 4;                         // node-per-wave blocks

  // layer-1 GEMM and edge scatter overlapped in ONE launch (independent)
  k_scatgemm<<<GB + SCATB, 256, 0, stream>>>(x16, WP1l, b1l, WP1r, b1r,
                                             xl16, xr, ei, ei + NE, ew,
                                             meansum, starts, counts, emeta);
  k_fused<<<nbn, 256, 0, stream>>>(xl16, xr, emeta, starts, We1, at1, bi1, hb16);
  // layer 2
  k_gemmM<HID><<<GB, 256, 0, stream>>>(hb16, WP2l, b2l, WP2r, b2r, xl16, xr, NN);
  k_fused<<<nbn, 256, 0, stream>>>(xl16, xr, emeta, starts, We2, at2, bi2, hb16);
  // pool + head (no atomics: batch is sorted -> contiguous graph ranges)
  k_pool<<<NG, 256, 0, stream>>>(hb16, gs, Wlin, blin, (float*)d_out);
}